// Round 1
// baseline (294.284 us; speedup 1.0000x reference)
//
#include <hip/hip_runtime.h>
#include <math.h>

#define NS   2048
#define TL   81
#define NBN  15
#define DA   48
#define SQL  31
#define KD   1488   // SEQ*D_ATT
#define DL   256
#define MID  40

#define INV_SQRT_BN 0.99999500003749969f   // 1/sqrt(1+1e-5)
#define SCALE_ATT   0.35355339059327373f   // 1/sqrt(8)

// ---------------- Kernel 1: per-sample encoder + LN + attention + proj -> y2 ----------------
__global__ __launch_bounds__(256)
void attn_kernel(const float* __restrict__ x5, const float* __restrict__ noise,
                 const float* __restrict__ enc_w, const float* __restrict__ enc_b,
                 const float* __restrict__ enc_g, const float* __restrict__ enc_bb,
                 const float* __restrict__ ln_a, const float* __restrict__ ln_b,
                 const float* __restrict__ wq, const float* __restrict__ bq,
                 const float* __restrict__ wk, const float* __restrict__ bk,
                 const float* __restrict__ wv, const float* __restrict__ bv,
                 const float* __restrict__ wo, const float* __restrict__ bo,
                 float* __restrict__ y2)
{
    __shared__ float s93[96];
    __shared__ float sy[32*49];                     // y after enc+relu  [s][f], stride 49
    __shared__ float sh[32*49];                     // h after LN; reused as ctx
    __shared__ float sW[3*48*49];                   // wq|wk|wv staged; arr0 reused for wo
    __shared__ __align__(16) float sQKV[32*148];    // [s][arr*48+f]
    __shared__ float smean[32], sinv[32];

    const int tid = threadIdx.x;
    const int n = blockIdx.x;

    // ---- phase 0: load mid-frame (root-subtracted) + noise; stage wq/wk/wv ----
    if (tid < 93) {
        float v;
        if (tid < 48) {
            const float* base = x5 + ((size_t)n*TL + MID)*48;
            v = base[tid] - base[tid % 3];          // x5 - root (joint 0)
        } else {
            v = noise[(size_t)n*45 + (tid-48)];
        }
        s93[tid] = v;
    }
    #pragma unroll
    for (int l=0; l<9; l++){
        int idx = tid + l*256;                      // 0..2303
        int f = idx/48, c = idx - f*48;
        int o = f*49 + c;
        sW[o]        = wq[idx];
        sW[2352 + o] = wk[idx];
        sW[4704 + o] = wv[idx];
    }
    __syncthreads();

    // ---- phase 1: encoder + BN + relu ----
    for (int idx=tid; idx<SQL*DA; idx+=256){
        int s = idx/48, f = idx - s*48;
        float a = enc_b[f]
                + s93[s*3+0]*enc_w[f*3+0]
                + s93[s*3+1]*enc_w[f*3+1]
                + s93[s*3+2]*enc_w[f*3+2];
        float v = a * (enc_g[f]*INV_SQRT_BN) + enc_bb[f];
        sy[s*49+f] = fmaxf(v, 0.0f);
    }
    __syncthreads();

    // ---- phase 2: layer-norm stats (divisor 47, eps on std) ----
    if (tid < SQL){
        float m = 0.f;
        for (int f=0; f<48; f++) m += sy[tid*49+f];
        m *= (1.0f/48.0f);
        float vs = 0.f;
        for (int f=0; f<48; f++){ float d = sy[tid*49+f]-m; vs += d*d; }
        float sd = sqrtf(vs * (1.0f/47.0f));
        smean[tid] = m;
        sinv[tid]  = 1.0f/(sd + 1e-6f);
    }
    __syncthreads();

    // ---- phase 3: apply LN ----
    for (int idx=tid; idx<SQL*DA; idx+=256){
        int s = idx/48, f = idx - s*48;
        sh[s*49+f] = ln_a[f]*(sy[s*49+f]-smean[s])*sinv[s] + ln_b[f];
    }
    __syncthreads();

    // ---- phase 4: QKV (register-tiled 4s x 6F, 192 threads) ----
    if (tid < 192){
        const int sg = tid/24, fg = tid - (tid/24)*24;
        const int arr = fg >> 3;                    // 0..2 -> q,k,v
        const int f0  = (fg & 7)*6;
        const float* wb = sW + arr*2352 + f0*49;
        const float* hb = sh + sg*4*49;
        float a0[6]={0,0,0,0,0,0}, a1[6]={0,0,0,0,0,0};
        float a2[6]={0,0,0,0,0,0}, a3[6]={0,0,0,0,0,0};
        for (int c=0; c<48; c++){
            float h0 = hb[c], h1 = hb[49+c], h2 = hb[98+c], h3 = hb[147+c];
            #pragma unroll
            for (int i=0;i<6;i++){
                float w = wb[i*49+c];
                a0[i] += h0*w; a1[i] += h1*w; a2[i] += h2*w; a3[i] += h3*w;
            }
        }
        const float* bias = (arr==0)? bq : (arr==1? bk : bv);
        #pragma unroll
        for (int i=0;i<6;i++){
            float b = bias[f0+i];
            int col = arr*48 + f0 + i;
            sQKV[(sg*4+0)*148 + col] = a0[i] + b;
            sQKV[(sg*4+1)*148 + col] = a1[i] + b;
            sQKV[(sg*4+2)*148 + col] = a2[i] + b;
            sQKV[(sg*4+3)*148 + col] = a3[i] + b;   // s=31 row is scratch, never read
        }
    }
    __syncthreads();

    // ---- phase 5: stage wo into sW arr0 (dead); attention (186 threads) -> ctx into sh ----
    #pragma unroll
    for (int l=0; l<9; l++){
        int idx = tid + l*256;
        sW[(idx/48)*49 + (idx%48)] = wo[idx];
    }
    if (tid < 186){
        const int hd = tid/31, qi = tid - (tid/31)*31;
        const float4 q0 = *(const float4*)(sQKV + qi*148 + hd*8);
        const float4 q1 = *(const float4*)(sQKV + qi*148 + hd*8 + 4);
        float sc[31]; float mx = -1e30f;
        for (int ki=0; ki<31; ki++){
            const float4 k0 = *(const float4*)(sQKV + ki*148 + 48 + hd*8);
            const float4 k1 = *(const float4*)(sQKV + ki*148 + 48 + hd*8 + 4);
            float d = q0.x*k0.x + q0.y*k0.y + q0.z*k0.z + q0.w*k0.w
                    + q1.x*k1.x + q1.y*k1.y + q1.z*k1.z + q1.w*k1.w;
            d *= SCALE_ATT;
            sc[ki] = d; mx = fmaxf(mx, d);
        }
        float ssum = 0.f;
        for (int ki=0; ki<31; ki++){ float e = expf(sc[ki]-mx); sc[ki]=e; ssum += e; }
        float rin = 1.0f/ssum;
        float4 c0 = {0,0,0,0}, c1 = {0,0,0,0};
        for (int ki=0; ki<31; ki++){
            float p = sc[ki];
            const float4 v0 = *(const float4*)(sQKV + ki*148 + 96 + hd*8);
            const float4 v1 = *(const float4*)(sQKV + ki*148 + 96 + hd*8 + 4);
            c0.x += p*v0.x; c0.y += p*v0.y; c0.z += p*v0.z; c0.w += p*v0.w;
            c1.x += p*v1.x; c1.y += p*v1.y; c1.z += p*v1.z; c1.w += p*v1.w;
        }
        float* cb = sh + qi*49 + hd*8;              // ctx overwrites h (dead)
        cb[0]=c0.x*rin; cb[1]=c0.y*rin; cb[2]=c0.z*rin; cb[3]=c0.w*rin;
        cb[4]=c1.x*rin; cb[5]=c1.y*rin; cb[6]=c1.z*rin; cb[7]=c1.w*rin;
    }
    __syncthreads();

    // ---- phase 6: proj + residual -> y2 (register-tiled 2s x 4f, 192 threads) ----
    if (tid < 192){
        const int sg = tid/12, fg = tid - (tid/12)*12;
        const int f0 = fg*4;
        const float* wb = sW + f0*49;               // wo
        const float* cb = sh + sg*2*49;             // ctx
        float a0[4]={0,0,0,0}, a1[4]={0,0,0,0};
        for (int c=0; c<48; c++){
            float x0 = cb[c], x1 = cb[49+c];
            #pragma unroll
            for (int i=0;i<4;i++){
                float w = wb[i*49+c];
                a0[i] += x0*w; a1[i] += x1*w;
            }
        }
        {
            int s = sg*2;
            if (s < 31){
                float* dst = y2 + (size_t)n*KD + s*48 + f0;
                const float* yb = sy + s*49 + f0;
                #pragma unroll
                for (int i=0;i<4;i++) dst[i] = yb[i] + a0[i] + bo[f0+i];
            }
        }
        {
            int s = sg*2+1;
            if (s < 31){
                float* dst = y2 + (size_t)n*KD + s*48 + f0;
                const float* yb = sy + s*49 + f0;
                #pragma unroll
                for (int i=0;i<4;i++) dst[i] = yb[i] + a1[i] + bo[f0+i];
            }
        }
    }
}

// ---------------- Kernel 2: y3 = leaky(bn1(y2 @ w1^T + b1))  (2048x256, K=1488) ----------------
__global__ __launch_bounds__(256)
void gemm1_kernel(const float* __restrict__ y2, const float* __restrict__ w1,
                  const float* __restrict__ b1, const float* __restrict__ g1,
                  const float* __restrict__ bb1, float* __restrict__ y3)
{
    __shared__ __align__(16) float sA[48*20];   // [kk][row(16)], stride 20 (b128-aligned)
    __shared__ float sB[48*64];                 // [kk][col]
    const int tid = threadIdx.x;
    const int bx = blockIdx.x;                  // 512 blocks
    const int m0 = (bx >> 2) * 16;
    const int n0 = (bx & 3) * 64;
    const int c  = tid & 63;
    const int r0 = (tid >> 6) * 4;
    float acc0=0.f, acc1=0.f, acc2=0.f, acc3=0.f;

    for (int it=0; it<31; ++it){
        const int k0 = it*48;
        if (tid < 192){
            int r = tid/12, kb = (tid%12)*4;
            float4 v = *(const float4*)(y2 + (size_t)(m0+r)*KD + k0 + kb);
            sA[(kb+0)*20+r]=v.x; sA[(kb+1)*20+r]=v.y; sA[(kb+2)*20+r]=v.z; sA[(kb+3)*20+r]=v.w;
        }
        #pragma unroll
        for (int l=0;l<3;l++){
            int idx = tid + l*256;              // 0..767
            int cc = idx/12, kb = (idx%12)*4;
            float4 v = *(const float4*)(w1 + (size_t)(n0+cc)*KD + k0 + kb);
            sB[(kb+0)*64+cc]=v.x; sB[(kb+1)*64+cc]=v.y; sB[(kb+2)*64+cc]=v.z; sB[(kb+3)*64+cc]=v.w;
        }
        __syncthreads();
        #pragma unroll
        for (int kk=0; kk<48; kk++){
            float b = sB[kk*64 + c];
            float4 a = *(const float4*)(sA + kk*20 + r0);   // wave-uniform broadcast
            acc0 += a.x*b; acc1 += a.y*b; acc2 += a.z*b; acc3 += a.w*b;
        }
        __syncthreads();
    }
    const int col = n0 + c;
    const float scl = g1[col]*INV_SQRT_BN;
    const float sft = bb1[col];
    const float bs  = b1[col];
    float v0 = (acc0+bs)*scl+sft; v0 = v0>=0.f? v0 : 0.01f*v0;
    float v1 = (acc1+bs)*scl+sft; v1 = v1>=0.f? v1 : 0.01f*v1;
    float v2 = (acc2+bs)*scl+sft; v2 = v2>=0.f? v2 : 0.01f*v2;
    float v3 = (acc3+bs)*scl+sft; v3 = v3>=0.f? v3 : 0.01f*v3;
    const int m = m0 + r0;
    y3[(size_t)(m+0)*DL + col] = v0;
    y3[(size_t)(m+1)*DL + col] = v1;
    y3[(size_t)(m+2)*DL + col] = v2;
    y3[(size_t)(m+3)*DL + col] = v3;
}

// ---------------- Kernel 3: y4 = leaky(y3 @ w2^T + b2); axis normalize + theta -> at ----------------
__global__ __launch_bounds__(256)
void head_kernel(const float* __restrict__ y3, const float* __restrict__ w2,
                 const float* __restrict__ b2, float* __restrict__ at)
{
    __shared__ float swc[64*60];                // w2 chunk, transposed [i][m]
    __shared__ __align__(16) float sy3[16*256];
    __shared__ float sy4[16*61];
    const int tid = threadIdx.x;
    const int n0 = blockIdx.x * 16;             // 128 blocks

    #pragma unroll
    for (int l=0;l<4;l++){
        int idx = tid + l*256;                  // 0..1023
        int s = idx >> 6, i4 = (idx & 63) << 2;
        *(float4*)(sy3 + s*256 + i4) = *(const float4*)(y3 + (size_t)(n0+s)*256 + i4);
    }

    float acc[4]; int ss[4], mm[4];
    #pragma unroll
    for (int l=0;l<4;l++){
        int uu = tid + l*256;
        ss[l]=0; mm[l]=0; acc[l]=0.f;
        if (uu < 960){ ss[l]=uu/60; mm[l]=uu-ss[l]*60; acc[l]=b2[mm[l]]; }
    }

    for (int ch=0; ch<4; ch++){
        const int i0 = ch*64;
        __syncthreads();
        #pragma unroll
        for (int l=0;l<15;l++){
            int idx = tid + l*256;              // 0..3839
            int m = idx >> 6, io = idx & 63;
            swc[io*60 + m] = w2[(size_t)m*256 + i0 + io];
        }
        __syncthreads();
        #pragma unroll
        for (int l=0;l<4;l++){
            int uu = tid + l*256;
            if (uu < 960){
                const float* yy = sy3 + ss[l]*256 + i0;
                float a = acc[l];
                #pragma unroll 8
                for (int io=0; io<64; io++) a += yy[io]*swc[io*60 + mm[l]];
                acc[l] = a;
            }
        }
    }
    __syncthreads();
    #pragma unroll
    for (int l=0;l<4;l++){
        int uu = tid + l*256;
        if (uu < 960){
            float a = acc[l];
            sy4[ss[l]*61 + mm[l]] = a>=0.f? a : 0.01f*a;
        }
    }
    __syncthreads();
    if (tid < 240){
        int s = tid/15, b = tid - s*15;
        const float* y4 = sy4 + s*61 + b*4;
        float ax=y4[0], ay=y4[1], az=y4[2], th=y4[3];
        float nr = sqrtf(ax*ax+ay*ay+az*az);
        float4 o;
        o.x = ax/nr; o.y = ay/nr; o.z = az/nr; o.w = th/81.0f;
        *(float4*)(at + (size_t)(n0+s)*60 + b*4) = o;
    }
}

// ---------------- Kernel 4: per-(n,t) Rodrigues + FK + ba_diff ----------------
__global__ __launch_bounds__(256)
void pose_kernel(const float* __restrict__ x5, const float* __restrict__ at,
                 float* __restrict__ out)
{
    const int gid = blockIdx.x*256 + threadIdx.x;
    if (gid >= NS*TL) return;
    const int n = gid / TL;
    const int t = gid - n*TL;
    const float ft = (float)t;

    float4 pv[12];
    {
        const float4* src = (const float4*)(x5 + (size_t)gid*48);
        #pragma unroll
        for (int i=0;i<12;i++) pv[i] = src[i];
    }
    float* p = (float*)pv;
    const float4* ab = (const float4*)(at + (size_t)n*60);

    float4 posv[12];
    float* pos = (float*)posv;
    pos[0]=p[0]; pos[1]=p[1]; pos[2]=p[2];      // root
    float ba[15];

    const int PJ[15] = {0,1,2,0,4,5,0,7,8,9,8,11,12,8,14};
    const int CJ[15] = {1,2,3,4,5,6,7,8,9,10,11,12,13,14,15};

    #pragma unroll
    for (int b=0;b<15;b++){
        const int pj = PJ[b], cj = CJ[b];
        float bx = p[cj*3+0]-p[pj*3+0];
        float by = p[cj*3+1]-p[pj*3+1];
        float bz = p[cj*3+2]-p[pj*3+2];
        float bl = sqrtf(bx*bx+by*by+bz*bz);
        float ux = bx/bl, uy = by/bl, uz = bz/bl;
        float mx, my, mz;
        if (b==6 || b==7){                       // FIXED_MASK zeros
            mx=ux; my=uy; mz=uz;
        } else {
            float4 a = ab[b];                    // axis (unit) + theta/81
            float ang = a.w * ft;                // signed angle == reference's |vaa| w/ signed k
            float cs = cosf(ang), sn = sinf(ang);
            float kd = a.x*ux + a.y*uy + a.z*uz;
            float cx = a.y*uz - a.z*uy;
            float cy = a.z*ux - a.x*uz;
            float cz = a.x*uy - a.y*ux;
            float oc = (1.0f-cs)*kd;
            mx = ux*cs + cx*sn + a.x*oc;
            my = uy*cs + cy*sn + a.y*oc;
            mz = uz*cs + cz*sn + a.z*oc;
        }
        ba[b] = 1.0f - (mx*ux+my*uy+mz*uz);
        pos[cj*3+0] = pos[pj*3+0] + mx*bl;
        pos[cj*3+1] = pos[pj*3+1] + my*bl;
        pos[cj*3+2] = pos[pj*3+2] + mz*bl;
    }

    {
        float4* dst = (float4*)(out + (size_t)gid*48);
        #pragma unroll
        for (int i=0;i<12;i++) dst[i] = posv[i];
    }
    {
        float* bd = out + (size_t)NS*TL*48 + (size_t)gid*15;
        #pragma unroll
        for (int b=0;b<15;b++) bd[b] = ba[b];
    }
}

extern "C" void kernel_launch(void* const* d_in, const int* in_sizes, int n_in,
                              void* d_out, int out_size, void* d_ws, size_t ws_size,
                              hipStream_t stream)
{
    const float* x5    = (const float*)d_in[0];
    const float* noise = (const float*)d_in[1];
    const float* enc_w = (const float*)d_in[2];
    const float* enc_b = (const float*)d_in[3];
    const float* enc_g = (const float*)d_in[4];
    const float* enc_bb= (const float*)d_in[5];
    const float* ln_a  = (const float*)d_in[6];
    const float* ln_b  = (const float*)d_in[7];
    const float* wq = (const float*)d_in[8];
    const float* bq = (const float*)d_in[9];
    const float* wk = (const float*)d_in[10];
    const float* bk = (const float*)d_in[11];
    const float* wv = (const float*)d_in[12];
    const float* bv = (const float*)d_in[13];
    const float* wo = (const float*)d_in[14];
    const float* bo = (const float*)d_in[15];
    const float* w1 = (const float*)d_in[16];
    const float* b1 = (const float*)d_in[17];
    const float* g1 = (const float*)d_in[18];
    const float* bb1= (const float*)d_in[19];
    const float* w2 = (const float*)d_in[20];
    const float* b2 = (const float*)d_in[21];
    float* out = (float*)d_out;

    float* ws = (float*)d_ws;
    float* y2 = ws;                          // 2048*1488 f32 = 12.2 MB
    float* y3 = y2 + (size_t)NS*KD;          // 2048*256  f32 =  2.0 MB
    float* at = y3 + (size_t)NS*DL;          // 2048*60   f32 =  0.5 MB

    attn_kernel<<<NS, 256, 0, stream>>>(x5, noise, enc_w, enc_b, enc_g, enc_bb,
                                        ln_a, ln_b, wq,bq,wk,bk,wv,bv,wo,bo, y2);
    gemm1_kernel<<<512, 256, 0, stream>>>(y2, w1, b1, g1, bb1, y3);
    head_kernel<<<128, 256, 0, stream>>>(y3, w2, b2, at);
    pose_kernel<<<(NS*TL+255)/256, 256, 0, stream>>>(x5, at, out);

    (void)in_sizes; (void)n_in; (void)out_size; (void)ws_size;
}

// Round 2
// 252.195 us; speedup vs baseline: 1.1669x; 1.1669x over previous
//
#include <hip/hip_runtime.h>
#include <math.h>

#define NS   2048
#define TL   81
#define NBN  15
#define DA   48
#define SQL  31
#define KD   1488   // SEQ*D_ATT
#define DL   256
#define MID  40

#define INV_SQRT_BN 0.99999500003749969f   // 1/sqrt(1+1e-5)
#define SCALE_ATT   0.35355339059327373f   // 1/sqrt(8)

// ---------------- Kernel 1: per-sample encoder + LN + attention + proj -> y2 ----------------
__global__ __launch_bounds__(256)
void attn_kernel(const float* __restrict__ x5, const float* __restrict__ noise,
                 const float* __restrict__ enc_w, const float* __restrict__ enc_b,
                 const float* __restrict__ enc_g, const float* __restrict__ enc_bb,
                 const float* __restrict__ ln_a, const float* __restrict__ ln_b,
                 const float* __restrict__ wq, const float* __restrict__ bq,
                 const float* __restrict__ wk, const float* __restrict__ bk,
                 const float* __restrict__ wv, const float* __restrict__ bv,
                 const float* __restrict__ wo, const float* __restrict__ bo,
                 float* __restrict__ y2)
{
    __shared__ float s93[96];
    __shared__ float sy[32*49];                     // y after enc+relu  [s][f], stride 49
    __shared__ float sh[32*49];                     // h after LN; reused as ctx
    __shared__ float sW[3*48*49];                   // wq|wk|wv staged; arr0 reused for wo
    __shared__ __align__(16) float sQKV[32*148];    // [s][arr*48+f]
    __shared__ float smean[32], sinv[32];

    const int tid = threadIdx.x;
    const int n = blockIdx.x;

    // ---- phase 0: load mid-frame (root-subtracted) + noise; stage wq/wk/wv ----
    if (tid < 93) {
        float v;
        if (tid < 48) {
            const float* base = x5 + ((size_t)n*TL + MID)*48;
            v = base[tid] - base[tid % 3];          // x5 - root (joint 0)
        } else {
            v = noise[(size_t)n*45 + (tid-48)];
        }
        s93[tid] = v;
    }
    #pragma unroll
    for (int l=0; l<9; l++){
        int idx = tid + l*256;                      // 0..2303
        int f = idx/48, c = idx - f*48;
        int o = f*49 + c;
        sW[o]        = wq[idx];
        sW[2352 + o] = wk[idx];
        sW[4704 + o] = wv[idx];
    }
    __syncthreads();

    // ---- phase 1: encoder + BN + relu ----
    for (int idx=tid; idx<SQL*DA; idx+=256){
        int s = idx/48, f = idx - s*48;
        float a = enc_b[f]
                + s93[s*3+0]*enc_w[f*3+0]
                + s93[s*3+1]*enc_w[f*3+1]
                + s93[s*3+2]*enc_w[f*3+2];
        float v = a * (enc_g[f]*INV_SQRT_BN) + enc_bb[f];
        sy[s*49+f] = fmaxf(v, 0.0f);
    }
    __syncthreads();

    // ---- phase 2: layer-norm stats (divisor 47, eps on std) ----
    if (tid < SQL){
        float m = 0.f;
        for (int f=0; f<48; f++) m += sy[tid*49+f];
        m *= (1.0f/48.0f);
        float vs = 0.f;
        for (int f=0; f<48; f++){ float d = sy[tid*49+f]-m; vs += d*d; }
        float sd = sqrtf(vs * (1.0f/47.0f));
        smean[tid] = m;
        sinv[tid]  = 1.0f/(sd + 1e-6f);
    }
    __syncthreads();

    // ---- phase 3: apply LN ----
    for (int idx=tid; idx<SQL*DA; idx+=256){
        int s = idx/48, f = idx - s*48;
        sh[s*49+f] = ln_a[f]*(sy[s*49+f]-smean[s])*sinv[s] + ln_b[f];
    }
    __syncthreads();

    // ---- phase 4: QKV (register-tiled 4s x 6F, 192 threads) ----
    if (tid < 192){
        const int sg = tid/24, fg = tid - (tid/24)*24;
        const int arr = fg >> 3;                    // 0..2 -> q,k,v
        const int f0  = (fg & 7)*6;
        const float* wb = sW + arr*2352 + f0*49;
        const float* hb = sh + sg*4*49;
        float a0[6]={0,0,0,0,0,0}, a1[6]={0,0,0,0,0,0};
        float a2[6]={0,0,0,0,0,0}, a3[6]={0,0,0,0,0,0};
        for (int c=0; c<48; c++){
            float h0 = hb[c], h1 = hb[49+c], h2 = hb[98+c], h3 = hb[147+c];
            #pragma unroll
            for (int i=0;i<6;i++){
                float w = wb[i*49+c];
                a0[i] += h0*w; a1[i] += h1*w; a2[i] += h2*w; a3[i] += h3*w;
            }
        }
        const float* bias = (arr==0)? bq : (arr==1? bk : bv);
        #pragma unroll
        for (int i=0;i<6;i++){
            float b = bias[f0+i];
            int col = arr*48 + f0 + i;
            sQKV[(sg*4+0)*148 + col] = a0[i] + b;
            sQKV[(sg*4+1)*148 + col] = a1[i] + b;
            sQKV[(sg*4+2)*148 + col] = a2[i] + b;
            sQKV[(sg*4+3)*148 + col] = a3[i] + b;   // s=31 row is scratch, never read
        }
    }
    __syncthreads();

    // ---- phase 5: stage wo into sW arr0 (dead); attention (186 threads) -> ctx into sh ----
    #pragma unroll
    for (int l=0; l<9; l++){
        int idx = tid + l*256;
        sW[(idx/48)*49 + (idx%48)] = wo[idx];
    }
    if (tid < 186){
        const int hd = tid/31, qi = tid - (tid/31)*31;
        const float4 q0 = *(const float4*)(sQKV + qi*148 + hd*8);
        const float4 q1 = *(const float4*)(sQKV + qi*148 + hd*8 + 4);
        float sc[31]; float mx = -1e30f;
        for (int ki=0; ki<31; ki++){
            const float4 k0 = *(const float4*)(sQKV + ki*148 + 48 + hd*8);
            const float4 k1 = *(const float4*)(sQKV + ki*148 + 48 + hd*8 + 4);
            float d = q0.x*k0.x + q0.y*k0.y + q0.z*k0.z + q0.w*k0.w
                    + q1.x*k1.x + q1.y*k1.y + q1.z*k1.z + q1.w*k1.w;
            d *= SCALE_ATT;
            sc[ki] = d; mx = fmaxf(mx, d);
        }
        float ssum = 0.f;
        for (int ki=0; ki<31; ki++){ float e = expf(sc[ki]-mx); sc[ki]=e; ssum += e; }
        float rin = 1.0f/ssum;
        float4 c0 = {0,0,0,0}, c1 = {0,0,0,0};
        for (int ki=0; ki<31; ki++){
            float p = sc[ki];
            const float4 v0 = *(const float4*)(sQKV + ki*148 + 96 + hd*8);
            const float4 v1 = *(const float4*)(sQKV + ki*148 + 96 + hd*8 + 4);
            c0.x += p*v0.x; c0.y += p*v0.y; c0.z += p*v0.z; c0.w += p*v0.w;
            c1.x += p*v1.x; c1.y += p*v1.y; c1.z += p*v1.z; c1.w += p*v1.w;
        }
        float* cb = sh + qi*49 + hd*8;              // ctx overwrites h (dead)
        cb[0]=c0.x*rin; cb[1]=c0.y*rin; cb[2]=c0.z*rin; cb[3]=c0.w*rin;
        cb[4]=c1.x*rin; cb[5]=c1.y*rin; cb[6]=c1.z*rin; cb[7]=c1.w*rin;
    }
    __syncthreads();

    // ---- phase 6: proj + residual -> y2 (register-tiled 2s x 4f, 192 threads) ----
    if (tid < 192){
        const int sg = tid/12, fg = tid - (tid/12)*12;
        const int f0 = fg*4;
        const float* wb = sW + f0*49;               // wo
        const float* cb = sh + sg*2*49;             // ctx
        float a0[4]={0,0,0,0}, a1[4]={0,0,0,0};
        for (int c=0; c<48; c++){
            float x0 = cb[c], x1 = cb[49+c];
            #pragma unroll
            for (int i=0;i<4;i++){
                float w = wb[i*49+c];
                a0[i] += x0*w; a1[i] += x1*w;
            }
        }
        {
            int s = sg*2;
            if (s < 31){
                float* dst = y2 + (size_t)n*KD + s*48 + f0;
                const float* yb = sy + s*49 + f0;
                #pragma unroll
                for (int i=0;i<4;i++) dst[i] = yb[i] + a0[i] + bo[f0+i];
            }
        }
        {
            int s = sg*2+1;
            if (s < 31){
                float* dst = y2 + (size_t)n*KD + s*48 + f0;
                const float* yb = sy + s*49 + f0;
                #pragma unroll
                for (int i=0;i<4;i++) dst[i] = yb[i] + a1[i] + bo[f0+i];
            }
        }
    }
}

// ---------------- Kernel 2 v2: raw dot C = y2 @ w1^T, K-split 6 ----------------
// M-tile 16, N full 256, K-chunk 8 (31 chunks per split). Thread = 4 rows x 4 cols.
// use_partial: write to y3p[split] slices; else atomicAdd into y3raw (pre-zeroed).
#define KSP 6
#define KPS 248     // 1488/6
#define KCH 8

__global__ __launch_bounds__(256)
void gemm1_kernel(const float* __restrict__ y2, const float* __restrict__ w1,
                  float* __restrict__ y3raw, int use_partial)
{
    __shared__ __align__(16) float sB[KCH*256];     // [kk][n]  8KB
    __shared__ __align__(16) float sA[KCH*20];      // [kk][m]  640B
    const int tid = threadIdx.x;
    const int bx = blockIdx.x;                      // 768 blocks
    const int m0 = (bx & 127) * 16;
    const int split = bx >> 7;                      // 0..5
    const int ks0 = split * KPS;
    const int c0 = (tid & 15)*4 + (tid >> 6)*64;    // output cols c0..c0+3
    const int r0 = ((tid >> 4) & 3)*4;              // output rows r0..r0+3

    const int bn = tid >> 1;                        // B staging: row within half
    const int bg = (tid & 1)*4;                     // kq
    const int ar = tid >> 1;                        // A staging (tid<32)
    const int ag = (tid & 1)*4;

    float acc[4][4];
    #pragma unroll
    for (int i=0;i<4;i++)
        #pragma unroll
        for (int j=0;j<4;j++) acc[i][j]=0.f;

    for (int ch=0; ch<31; ch++){
        const int k0 = ks0 + ch*KCH;
        // global loads first (latency overlapped with other blocks' compute)
        float4 b0v = *(const float4*)(w1 + (size_t)bn*KD        + k0 + bg);
        float4 b1v = *(const float4*)(w1 + (size_t)(bn+128)*KD  + k0 + bg);
        float4 av;
        if (tid < 32) av = *(const float4*)(y2 + (size_t)(m0+ar)*KD + k0 + ag);
        __syncthreads();
        // transposed stores: bank = n%32 across lanes -> 2-way (free)
        sB[(bg+0)*256 + bn] = b0v.x;  sB[(bg+1)*256 + bn] = b0v.y;
        sB[(bg+2)*256 + bn] = b0v.z;  sB[(bg+3)*256 + bn] = b0v.w;
        sB[(bg+0)*256 + bn+128] = b1v.x;  sB[(bg+1)*256 + bn+128] = b1v.y;
        sB[(bg+2)*256 + bn+128] = b1v.z;  sB[(bg+3)*256 + bn+128] = b1v.w;
        if (tid < 32){
            sA[(ag+0)*20 + ar] = av.x;  sA[(ag+1)*20 + ar] = av.y;
            sA[(ag+2)*20 + ar] = av.z;  sA[(ag+3)*20 + ar] = av.w;
        }
        __syncthreads();
        #pragma unroll
        for (int kk=0; kk<KCH; kk++){
            float4 b = *(const float4*)(sB + kk*256 + c0);  // 16 addr x 4-lane bcast
            float4 a = *(const float4*)(sA + kk*20 + r0);   // 4 addr broadcast
            acc[0][0] += a.x*b.x; acc[0][1] += a.x*b.y; acc[0][2] += a.x*b.z; acc[0][3] += a.x*b.w;
            acc[1][0] += a.y*b.x; acc[1][1] += a.y*b.y; acc[1][2] += a.y*b.z; acc[1][3] += a.y*b.w;
            acc[2][0] += a.z*b.x; acc[2][1] += a.z*b.y; acc[2][2] += a.z*b.z; acc[2][3] += a.z*b.w;
            acc[3][0] += a.w*b.x; acc[3][1] += a.w*b.y; acc[3][2] += a.w*b.z; acc[3][3] += a.w*b.w;
        }
    }

    if (use_partial){
        float* dst = y3raw + (size_t)split*NS*DL;
        #pragma unroll
        for (int i=0;i<4;i++){
            float4 v; v.x=acc[i][0]; v.y=acc[i][1]; v.z=acc[i][2]; v.w=acc[i][3];
            *(float4*)(dst + (size_t)(m0+r0+i)*DL + c0) = v;
        }
    } else {
        #pragma unroll
        for (int i=0;i<4;i++)
            #pragma unroll
            for (int j=0;j<4;j++)
                atomicAdd(y3raw + (size_t)(m0+r0+i)*DL + c0 + j, acc[i][j]);
    }
}

// ---------------- Kernel 3: sum K-splits + bias/BN/leaky; y4 = leaky(y3 @ w2^T + b2); axis/theta ----------------
__global__ __launch_bounds__(256)
void head_kernel(const float* __restrict__ y3raw, const float* __restrict__ w2,
                 const float* __restrict__ b2, const float* __restrict__ b1,
                 const float* __restrict__ g1, const float* __restrict__ bb1,
                 float* __restrict__ at, int nsl)
{
    __shared__ float swc[64*60];                // w2 chunk, transposed [i][m]
    __shared__ __align__(16) float sy3[16*256];
    __shared__ float sy4[16*61];
    const int tid = threadIdx.x;
    const int n0 = blockIdx.x * 16;             // 128 blocks

    #pragma unroll
    for (int l=0;l<4;l++){
        int idx = tid + l*256;                  // 0..1023
        int s = idx >> 6, i4 = (idx & 63) << 2;
        const float* src = y3raw + (size_t)(n0+s)*256 + i4;
        float4 v = *(const float4*)(src);
        if (nsl == 6){
            #pragma unroll
            for (int sl=1; sl<6; sl++){
                float4 p = *(const float4*)(src + (size_t)sl*NS*DL);
                v.x += p.x; v.y += p.y; v.z += p.z; v.w += p.w;
            }
        }
        const float4 vb = *(const float4*)(b1 + i4);
        const float4 vg = *(const float4*)(g1 + i4);
        const float4 vs = *(const float4*)(bb1 + i4);
        v.x = (v.x + vb.x)*(vg.x*INV_SQRT_BN) + vs.x;  v.x = v.x>=0.f? v.x : 0.01f*v.x;
        v.y = (v.y + vb.y)*(vg.y*INV_SQRT_BN) + vs.y;  v.y = v.y>=0.f? v.y : 0.01f*v.y;
        v.z = (v.z + vb.z)*(vg.z*INV_SQRT_BN) + vs.z;  v.z = v.z>=0.f? v.z : 0.01f*v.z;
        v.w = (v.w + vb.w)*(vg.w*INV_SQRT_BN) + vs.w;  v.w = v.w>=0.f? v.w : 0.01f*v.w;
        *(float4*)(sy3 + s*256 + i4) = v;
    }

    float acc[4]; int ss[4], mm[4];
    #pragma unroll
    for (int l=0;l<4;l++){
        int uu = tid + l*256;
        ss[l]=0; mm[l]=0; acc[l]=0.f;
        if (uu < 960){ ss[l]=uu/60; mm[l]=uu-ss[l]*60; acc[l]=b2[mm[l]]; }
    }

    for (int ch=0; ch<4; ch++){
        const int i0 = ch*64;
        __syncthreads();
        #pragma unroll
        for (int l=0;l<15;l++){
            int idx = tid + l*256;              // 0..3839
            int m = idx >> 6, io = idx & 63;
            swc[io*60 + m] = w2[(size_t)m*256 + i0 + io];
        }
        __syncthreads();
        #pragma unroll
        for (int l=0;l<4;l++){
            int uu = tid + l*256;
            if (uu < 960){
                const float* yy = sy3 + ss[l]*256 + i0;
                float a = acc[l];
                #pragma unroll 8
                for (int io=0; io<64; io++) a += yy[io]*swc[io*60 + mm[l]];
                acc[l] = a;
            }
        }
    }
    __syncthreads();
    #pragma unroll
    for (int l=0;l<4;l++){
        int uu = tid + l*256;
        if (uu < 960){
            float a = acc[l];
            sy4[ss[l]*61 + mm[l]] = a>=0.f? a : 0.01f*a;
        }
    }
    __syncthreads();
    if (tid < 240){
        int s = tid/15, b = tid - s*15;
        const float* y4 = sy4 + s*61 + b*4;
        float ax=y4[0], ay=y4[1], az=y4[2], th=y4[3];
        float nr = sqrtf(ax*ax+ay*ay+az*az);
        float4 o;
        o.x = ax/nr; o.y = ay/nr; o.z = az/nr; o.w = th/81.0f;
        *(float4*)(at + (size_t)(n0+s)*60 + b*4) = o;
    }
}

// ---------------- Kernel 4: per-(n,t) Rodrigues + FK + ba_diff ----------------
__global__ __launch_bounds__(256)
void pose_kernel(const float* __restrict__ x5, const float* __restrict__ at,
                 float* __restrict__ out)
{
    const int gid = blockIdx.x*256 + threadIdx.x;
    if (gid >= NS*TL) return;
    const int n = gid / TL;
    const int t = gid - n*TL;
    const float ft = (float)t;

    float4 pv[12];
    {
        const float4* src = (const float4*)(x5 + (size_t)gid*48);
        #pragma unroll
        for (int i=0;i<12;i++) pv[i] = src[i];
    }
    float* p = (float*)pv;
    const float4* ab = (const float4*)(at + (size_t)n*60);

    float4 posv[12];
    float* pos = (float*)posv;
    pos[0]=p[0]; pos[1]=p[1]; pos[2]=p[2];      // root
    float ba[15];

    const int PJ[15] = {0,1,2,0,4,5,0,7,8,9,8,11,12,8,14};
    const int CJ[15] = {1,2,3,4,5,6,7,8,9,10,11,12,13,14,15};

    #pragma unroll
    for (int b=0;b<15;b++){
        const int pj = PJ[b], cj = CJ[b];
        float bx = p[cj*3+0]-p[pj*3+0];
        float by = p[cj*3+1]-p[pj*3+1];
        float bz = p[cj*3+2]-p[pj*3+2];
        float bl = sqrtf(bx*bx+by*by+bz*bz);
        float ux = bx/bl, uy = by/bl, uz = bz/bl;
        float mx, my, mz;
        if (b==6 || b==7){                       // FIXED_MASK zeros
            mx=ux; my=uy; mz=uz;
        } else {
            float4 a = ab[b];                    // axis (unit) + theta/81
            float ang = a.w * ft;                // signed angle == reference's |vaa| w/ signed k
            float cs = cosf(ang), sn = sinf(ang);
            float kd = a.x*ux + a.y*uy + a.z*uz;
            float cx = a.y*uz - a.z*uy;
            float cy = a.z*ux - a.x*uz;
            float cz = a.x*uy - a.y*ux;
            float oc = (1.0f-cs)*kd;
            mx = ux*cs + cx*sn + a.x*oc;
            my = uy*cs + cy*sn + a.y*oc;
            mz = uz*cs + cz*sn + a.z*oc;
        }
        ba[b] = 1.0f - (mx*ux+my*uy+mz*uz);
        pos[cj*3+0] = pos[pj*3+0] + mx*bl;
        pos[cj*3+1] = pos[pj*3+1] + my*bl;
        pos[cj*3+2] = pos[pj*3+2] + mz*bl;
    }

    {
        float4* dst = (float4*)(out + (size_t)gid*48);
        #pragma unroll
        for (int i=0;i<12;i++) dst[i] = posv[i];
    }
    {
        float* bd = out + (size_t)NS*TL*48 + (size_t)gid*15;
        #pragma unroll
        for (int b=0;b<15;b++) bd[b] = ba[b];
    }
}

extern "C" void kernel_launch(void* const* d_in, const int* in_sizes, int n_in,
                              void* d_out, int out_size, void* d_ws, size_t ws_size,
                              hipStream_t stream)
{
    const float* x5    = (const float*)d_in[0];
    const float* noise = (const float*)d_in[1];
    const float* enc_w = (const float*)d_in[2];
    const float* enc_b = (const float*)d_in[3];
    const float* enc_g = (const float*)d_in[4];
    const float* enc_bb= (const float*)d_in[5];
    const float* ln_a  = (const float*)d_in[6];
    const float* ln_b  = (const float*)d_in[7];
    const float* wq = (const float*)d_in[8];
    const float* bq = (const float*)d_in[9];
    const float* wk = (const float*)d_in[10];
    const float* bk = (const float*)d_in[11];
    const float* wv = (const float*)d_in[12];
    const float* bv = (const float*)d_in[13];
    const float* wo = (const float*)d_in[14];
    const float* bo = (const float*)d_in[15];
    const float* w1 = (const float*)d_in[16];
    const float* b1 = (const float*)d_in[17];
    const float* g1 = (const float*)d_in[18];
    const float* bb1= (const float*)d_in[19];
    const float* w2 = (const float*)d_in[20];
    const float* b2 = (const float*)d_in[21];
    float* out = (float*)d_out;

    float* ws = (float*)d_ws;
    float* y2 = ws;                              // 2048*1488 f32 = 12.2 MB
    float* y3 = y2 + (size_t)NS*KD;              // slice 0 (atomic) or 6 slices (partial)

    // partial path needs y2 + 6 slices + at
    const size_t need_partial = ((size_t)NS*KD + 6*(size_t)NS*DL + (size_t)NS*60) * 4;
    const int use_partial = (ws_size >= need_partial) ? 1 : 0;
    const int nsl = use_partial ? 6 : 1;
    float* at = y3 + (size_t)nsl*NS*DL;          // 2048*60 f32

    if (!use_partial)
        hipMemsetAsync(y3, 0, (size_t)NS*DL*sizeof(float), stream);

    attn_kernel<<<NS, 256, 0, stream>>>(x5, noise, enc_w, enc_b, enc_g, enc_bb,
                                        ln_a, ln_b, wq,bq,wk,bk,wv,bv,wo,bo, y2);
    gemm1_kernel<<<128*KSP, 256, 0, stream>>>(y2, w1, y3, use_partial);
    head_kernel<<<128, 256, 0, stream>>>(y3, w2, b2, b1, g1, bb1, at, nsl);
    pose_kernel<<<(NS*TL+255)/256, 256, 0, stream>>>(x5, at, out);

    (void)in_sizes; (void)n_in; (void)out_size;
}